// Round 8
// baseline (361.624 us; speedup 1.0000x reference)
//
#include <hip/hip_runtime.h>

// MNIST_RNN R8: barrier-free pair-split. Evidence: R6->R7 halved per-CU LDS
// weight traffic yet got SLOWER at identical samples/CU => LDS issue was
// never binding; the cost is latency/barrier exposure (2 syncthreads/t over
// all CU waves). New shape: 1 wave = 32 samples, 2 lanes/sample (5 hidden
// units each, h exchanged by __shfl_xor(.,1) -- validated in R2). Weights
// from LDS as 2-address ds_read_b128 broadcasts (pair rows 5 apart = 800B /
// 100 floats offset => disjoint bank groups, conflict-free). NO syncthreads
// in the t-loop: x double-buffer synced by one explicit s_waitcnt vmcnt(0)
// per t (wait for buf[cur], THEN issue prefetch of t+1 into buf[cur^1]).
// grid 1024 x block 64 -> 4 waves/CU, 1/SIMD; per-wave/t ~3.2k cyc VALU.

#define HDIM 10
#define DDIM 28
#define TSTEPS 28
#define SPW 32            // samples per wave

typedef const __attribute__((address_space(1))) unsigned int gu32;
typedef __attribute__((address_space(3))) unsigned int lu32;

__device__ __forceinline__ void gld_lds16(const float* g, float4* l) {
    __builtin_amdgcn_global_load_lds((gu32*)g, (lu32*)l, 16, 0, 0);
}

__device__ __forceinline__ float fast_sigmoid(float v) {
    return __builtin_amdgcn_rcpf(1.0f + __expf(-v));
}
__device__ __forceinline__ float fast_tanh(float v) {
    return 2.0f * __builtin_amdgcn_rcpf(1.0f + __expf(-2.0f * v)) - 1.0f;
}

__global__ __launch_bounds__(64) void lstm2_cls_kernel(
    const float* __restrict__ x,
    const float* __restrict__ w_ih0, const float* __restrict__ w_hh0,
    const float* __restrict__ b_ih0, const float* __restrict__ b_hh0,
    const float* __restrict__ w_ih1, const float* __restrict__ w_hh1,
    const float* __restrict__ b_ih1, const float* __restrict__ b_hh1,
    const float* __restrict__ w_cls, const float* __restrict__ b_cls,
    float* __restrict__ out)
{
    __shared__ float s_w0[40 * 40];      // [row][28 x | 10 h | 2 pad]  6400 B
    __shared__ float s_w1[40 * 20];      // [row][10 ih | 10 hh]        3200 B
    __shared__ float s_b0[40], s_b1[40]; //                              320 B
    __shared__ float4 s_x[2][SPW * 7];   // [buf][sample*7 + v]         7168 B

    const int tid = threadIdx.x;           // == lane (block = 1 wave)
    const int par = tid & 1;               // 0: units 0..4, 1: units 5..9
    const int ubase = par * 5;
    const int sl  = tid >> 1;              // sample within wave
    const int b0s = blockIdx.x * SPW;
    const int sample = b0s + sl;

    // ---- x DMA source pointers: slot s = (sample_l*7 + v); 4 batches ----
    const float* gsrc[4];
    #pragma unroll
    for (int k = 0; k < 4; ++k) {
        const int sid = tid + 64 * k;          // slot 0..255 (224 used)
        const int sm = sid / 7, v = sid - 7 * sm;
        gsrc[k] = x + (size_t)(b0s + sm) * (TSTEPS * DDIM) + 4 * v;
    }
    // t=0 tile into buf 0
    #pragma unroll
    for (int k = 0; k < 3; ++k) gld_lds16(gsrc[k], &s_x[0][tid + 64 * k]);
    if (tid < 32) gld_lds16(gsrc[3], &s_x[0][tid + 192]);

    // ---- stage weights (single wave; LDS pipe is in-order per wave) ----
    for (int i = tid; i < 40 * 40; i += 64) {
        const int r = i / 40, c = i - r * 40;
        float v = 0.0f;
        if (c < DDIM)             v = w_ih0[r * DDIM + c];
        else if (c < DDIM + HDIM) v = w_hh0[r * HDIM + (c - DDIM)];
        s_w0[i] = v;
    }
    for (int i = tid; i < 40 * 20; i += 64) {
        const int r = i / 20, c = i - r * 20;
        s_w1[i] = (c < HDIM) ? w_ih1[r * HDIM + c] : w_hh1[r * HDIM + (c - HDIM)];
    }
    for (int i = tid; i < 40; i += 64) {
        s_b0[i] = b_ih0[i] + b_hh0[i];
        s_b1[i] = b_ih1[i] + b_hh1[i];
    }
    __syncthreads();   // one-time; single-wave so cheap

    // state: full h vectors (post-exchange), own c halves
    float h0f[HDIM], h1f[HDIM], c0[5], c1[5];
    #pragma unroll
    for (int j = 0; j < HDIM; ++j) { h0f[j] = 0.0f; h1f[j] = 0.0f; }
    #pragma unroll
    for (int k = 0; k < 5; ++k) { c0[k] = 0.0f; c1[k] = 0.0f; }

    // one gate pass, layer 0: 5 rows of gate q -> res[5]
    auto l0_pass = [&](int q, const float4* xr4, float res[5]) {
        #pragma unroll
        for (int k = 0; k < 5; ++k) {
            const int r = q * 10 + ubase + k;
            const float4* wp = (const float4*)&s_w0[r * 40];
            float acc = s_b0[r];
            #pragma unroll
            for (int v = 0; v < 7; ++v) {
                const float4 w = wp[v];
                acc += xr4[v].x*w.x + xr4[v].y*w.y + xr4[v].z*w.z + xr4[v].w*w.w;
            }
            { const float4 w = wp[7]; acc += h0f[0]*w.x + h0f[1]*w.y + h0f[2]*w.z + h0f[3]*w.w; }
            { const float4 w = wp[8]; acc += h0f[4]*w.x + h0f[5]*w.y + h0f[6]*w.z + h0f[7]*w.w; }
            { const float4 w = wp[9]; acc += h0f[8]*w.x + h0f[9]*w.y; }
            res[k] = acc;
        }
    };
    auto l1_pass = [&](int q, float res[5]) {
        #pragma unroll
        for (int k = 0; k < 5; ++k) {
            const int r = q * 10 + ubase + k;
            const float4* wp = (const float4*)&s_w1[r * 20];
            float acc = s_b1[r];
            { const float4 w = wp[0]; acc += h0f[0]*w.x + h0f[1]*w.y + h0f[2]*w.z + h0f[3]*w.w; }
            { const float4 w = wp[1]; acc += h0f[4]*w.x + h0f[5]*w.y + h0f[6]*w.z + h0f[7]*w.w; }
            { const float4 w = wp[2]; acc += h0f[8]*w.x + h0f[9]*w.y + h1f[0]*w.z + h1f[1]*w.w; }
            { const float4 w = wp[3]; acc += h1f[2]*w.x + h1f[3]*w.y + h1f[4]*w.z + h1f[5]*w.w; }
            { const float4 w = wp[4]; acc += h1f[6]*w.x + h1f[7]*w.y + h1f[8]*w.z + h1f[9]*w.w; }
            res[k] = acc;
        }
    };

    #pragma unroll 1
    for (int t = 0; t < TSTEPS; ++t) {
        const int cur = t & 1;

        // buf[cur]'s DMA (issued last iter / preamble) must be complete.
        // Explicit wait FIRST, then issue next prefetch (so the prefetch
        // stays in flight through this iteration's compute).
        __builtin_amdgcn_s_waitcnt(0x0F70);   // vmcnt(0), lgkm/exp unconstrained

        if (t + 1 < TSTEPS) {
            #pragma unroll
            for (int k = 0; k < 3; ++k) {
                gsrc[k] += DDIM;
                gld_lds16(gsrc[k], &s_x[cur ^ 1][tid + 64 * k]);
            }
            if (tid < 32) { gsrc[3] += DDIM; gld_lds16(gsrc[3], &s_x[cur ^ 1][tid + 192]); }
        }

        // x row (pair lanes share address -> broadcast)
        float4 xr4[7];
        {
            const float4* xp = &s_x[cur][sl * 7];
            #pragma unroll
            for (int v = 0; v < 7; ++v) xr4[v] = xp[v];
        }

        // ---------- layer 0 ----------
        {
            float gg[5]; l0_pass(2, xr4, gg);
            #pragma unroll
            for (int k = 0; k < 5; ++k) gg[k] = fast_tanh(gg[k]);
            float ii[5]; l0_pass(0, xr4, ii);
            #pragma unroll
            for (int k = 0; k < 5; ++k) gg[k] *= fast_sigmoid(ii[k]);
            float ff[5]; l0_pass(1, xr4, ff);
            #pragma unroll
            for (int k = 0; k < 5; ++k) c0[k] = fast_sigmoid(ff[k]) * c0[k] + gg[k];
            float oo[5]; l0_pass(3, xr4, oo);
            float hn[5];
            #pragma unroll
            for (int k = 0; k < 5; ++k) hn[k] = fast_sigmoid(oo[k]) * fast_tanh(c0[k]);
            #pragma unroll
            for (int k = 0; k < 5; ++k) {
                const float p = __shfl_xor(hn[k], 1);
                h0f[k]     = par ? p     : hn[k];
                h0f[k + 5] = par ? hn[k] : p;
            }
        }

        // ---------- layer 1 ----------
        {
            float gg[5]; l1_pass(2, gg);
            #pragma unroll
            for (int k = 0; k < 5; ++k) gg[k] = fast_tanh(gg[k]);
            float ii[5]; l1_pass(0, ii);
            #pragma unroll
            for (int k = 0; k < 5; ++k) gg[k] *= fast_sigmoid(ii[k]);
            float ff[5]; l1_pass(1, ff);
            #pragma unroll
            for (int k = 0; k < 5; ++k) c1[k] = fast_sigmoid(ff[k]) * c1[k] + gg[k];
            float oo[5]; l1_pass(3, oo);
            float hn[5];
            #pragma unroll
            for (int k = 0; k < 5; ++k) hn[k] = fast_sigmoid(oo[k]) * fast_tanh(c1[k]);
            #pragma unroll
            for (int k = 0; k < 5; ++k) {
                const float p = __shfl_xor(hn[k], 1);
                h1f[k]     = par ? p     : hn[k];
                h1f[k + 5] = par ? hn[k] : p;
            }
        }
    }

    // ---------- classifier: even lane -> out 0..4, odd -> 5..9 ----------
    #pragma unroll
    for (int k = 0; k < 5; ++k) {
        const int o = ubase + k;
        float a = b_cls[o];
        const float* wc = w_cls + o * HDIM;
        #pragma unroll
        for (int j = 0; j < HDIM; ++j) a += h1f[j] * wc[j];
        out[(size_t)sample * 10 + o] = a;
    }
}

extern "C" void kernel_launch(void* const* d_in, const int* in_sizes, int n_in,
                              void* d_out, int out_size, void* d_ws, size_t ws_size,
                              hipStream_t stream) {
    const float* x     = (const float*)d_in[0];
    const float* w_ih0 = (const float*)d_in[1];
    const float* w_hh0 = (const float*)d_in[2];
    const float* b_ih0 = (const float*)d_in[3];
    const float* b_hh0 = (const float*)d_in[4];
    const float* w_ih1 = (const float*)d_in[5];
    const float* w_hh1 = (const float*)d_in[6];
    const float* b_ih1 = (const float*)d_in[7];
    const float* b_hh1 = (const float*)d_in[8];
    const float* w_cls = (const float*)d_in[9];
    const float* b_cls = (const float*)d_in[10];
    float* out = (float*)d_out;

    const int B = in_sizes[0] / (TSTEPS * DDIM);   // 32768
    const int grid = B / SPW;                      // 1024 blocks of 1 wave

    hipLaunchKernelGGL(lstm2_cls_kernel, dim3(grid), dim3(64), 0, stream,
                       x, w_ih0, w_hh0, b_ih0, b_hh0,
                       w_ih1, w_hh1, b_ih1, b_hh1,
                       w_cls, b_cls, out);
}

// Round 9
// 264.236 us; speedup vs baseline: 1.3686x; 1.3686x over previous
//
#include <hip/hip_runtime.h>

// MNIST_RNN R9: MFMA path. R3-R8 lesson: VALU formulations die on weight
// re-delivery latency (~0.2 float/cyc/CU scalar pipe; ds_read ~60cyc
// effective serial at low occupancy). Fix: weights live in REGISTERS as
// MFMA B-fragments (72 VGPR covers all of W0/W1 via split-bf16), one wave
// owns 16 samples end-to-end, zero barriers, per-wave-private LDS panels.
// Precision: A=[uhi,ulo,uhi], B=[whi,whi,wlo] K-concat => uhi*whi +
// ulo*whi + uhi*wlo (~1e-5 error). L0 K=114->4 mfma x3 Ntiles; L1 K=60->
// 2x3. Gates exit C-layout (m=4q+reg, n=lane&15) -> gbuf[n][m] -> c/h by
// (u=lane&15, 4 samples) -> h back to A-panels as bf16 hi/lo b16 writes.
// Intra-wave LDS RAW/WAR ordered by in-order DS pipe + compiler fences.
// x: 7 global loads/lane/t prefetched into VGPRs, converted in-kernel.

#define HDIM 10
#define DDIM 28
#define TSTEPS 28

typedef __attribute__((ext_vector_type(8))) short short8;
typedef __attribute__((ext_vector_type(4))) float f32x4;

__device__ __forceinline__ unsigned short bf16_rne(float f) {
    unsigned u = __builtin_bit_cast(unsigned, f);
    u += 0x7FFFu + ((u >> 16) & 1u);
    return (unsigned short)(u >> 16);
}
__device__ __forceinline__ float bf16_f(unsigned short h) {
    unsigned u = ((unsigned)h) << 16;
    return __builtin_bit_cast(float, u);
}
// a=1: sigmoid(v); a=2: tanh(v)  [act = a*rcp(1+exp(-a*v)) + 1-a]
__device__ __forceinline__ float act_eval(float v, float a) {
    return a * __builtin_amdgcn_rcpf(1.0f + __expf(-a * v)) + (1.0f - a);
}

#define FENCE() __asm volatile("" ::: "memory")

__global__ __launch_bounds__(64) void lstm2_mfma_kernel(
    const float* __restrict__ x,
    const float* __restrict__ w_ih0, const float* __restrict__ w_hh0,
    const float* __restrict__ b_ih0, const float* __restrict__ b_hh0,
    const float* __restrict__ w_ih1, const float* __restrict__ w_hh1,
    const float* __restrict__ b_ih1, const float* __restrict__ b_hh1,
    const float* __restrict__ w_cls, const float* __restrict__ b_cls,
    float* __restrict__ out)
{
    // per-wave-private panels (block = 1 wave)
    __shared__ unsigned short uA0[16 * 136]; // A0 rows: [xhi28|h0hi10|xlo28|h0lo10|xhi28|h0hi10|pad14], stride 136
    __shared__ unsigned short uA1[16 * 72];  // A1 rows: [h0hi|h1hi|h0lo|h1lo|h0hi|h1hi|pad], stride 72
    __shared__ float gbuf[48 * 20];          // activated gates [n][m], Mpad=20
    __shared__ float hfin[16 * 12];          // final h1 [m][u]

    const int l  = threadIdx.x;
    const int lm = l & 15;     // A-frag row m / B-frag & D col n / c-h unit u
    const int q  = l >> 4;     // quad: A/B k-offset 8q; D rows m=4q+r
    const int sbase = blockIdx.x * 16;

    // ---- zero A-panel pads (B pads are 0 too, but NaN*0=NaN in MFMA) ----
    for (int i = l; i < 16 * 22; i += 64) uA0[(i / 22) * 136 + 114 + (i % 22)] = 0;
    for (int i = l; i < 16 * 12; i += 64) uA1[(i / 12) * 72 + 60 + (i % 12)] = 0;

    // ---- build B-fragments in registers (once) ----
    // B0 k-zones: [0,38)=whi[k], [38,76)=whi[k-38], [76,114)=wlo[k-76], pad0
    //   w0 row n col k2: k2<28 -> w_ih0[n][k2], else w_hh0[n][k2-28]
    // B1 k-zones: [0,20)=whi1[k], [20,40)=whi1[k-20], [40,60)=wlo1[k-40], pad0
    //   w1 row n col k2: k2<10 -> w_ih1[n][k2], else w_hh1[n][k2-10]
    short8 B0[3][4], B1[3][2];
    #pragma unroll
    for (int T = 0; T < 3; ++T) {
        const int n = lm + 16 * T;
        #pragma unroll
        for (int c = 0; c < 4; ++c) {
            #pragma unroll
            for (int j = 0; j < 8; ++j) {
                const int kk = 32 * c + 8 * q + j;
                unsigned short bits = 0;
                if (n < 40 && kk < 114) {
                    int k2 = kk, want_lo = 0;
                    if (k2 >= 76)      { k2 -= 76; want_lo = 1; }
                    else if (k2 >= 38) { k2 -= 38; }
                    const float w = (k2 < 28) ? w_ih0[n * 28 + k2]
                                              : w_hh0[n * 10 + (k2 - 28)];
                    const unsigned short hi = bf16_rne(w);
                    bits = want_lo ? bf16_rne(w - bf16_f(hi)) : hi;
                }
                B0[T][c][j] = (short)bits;
            }
        }
        #pragma unroll
        for (int c = 0; c < 2; ++c) {
            #pragma unroll
            for (int j = 0; j < 8; ++j) {
                const int kk = 32 * c + 8 * q + j;
                unsigned short bits = 0;
                if (n < 40 && kk < 60) {
                    int k2 = kk, want_lo = 0;
                    if (k2 >= 40)      { k2 -= 40; want_lo = 1; }
                    else if (k2 >= 20) { k2 -= 20; }
                    const float w = (k2 < 10) ? w_ih1[n * 10 + k2]
                                              : w_hh1[n * 10 + (k2 - 10)];
                    const unsigned short hi = bf16_rne(w);
                    bits = want_lo ? bf16_rne(w - bf16_f(hi)) : hi;
                }
                B1[T][c][j] = (short)bits;
            }
        }
    }

    // biases (fold into MFMA C-init) + per-tile activation selector
    float bias0[3], bias1[3], aT[3];
    #pragma unroll
    for (int T = 0; T < 3; ++T) {
        const int n = lm + 16 * T;
        bias0[T] = (n < 40) ? (b_ih0[n] + b_hh0[n]) : 0.0f;
        bias1[T] = (n < 40) ? (b_ih1[n] + b_hh1[n]) : 0.0f;
        aT[T] = (n >= 20 && n < 30) ? 2.0f : 1.0f;   // g-gate rows -> tanh
    }

    // ---- x pipeline: lane owns 7 of the 448 (sample,d) elements ----
    const float* xp[7]; int xsm[7], xd[7]; float xn[7];
    #pragma unroll
    for (int i = 0; i < 7; ++i) {
        const int f = l + 64 * i;
        const int sm = f / 28, d = f - 28 * sm;
        xsm[i] = sm; xd[i] = d;
        xp[i] = x + (size_t)(sbase + sm) * (TSTEPS * DDIM) + d;
        xn[i] = xp[i][0];     // t = 0
    }
    // write x(0) zones
    #pragma unroll
    for (int i = 0; i < 7; ++i) {
        const unsigned short hi = bf16_rne(xn[i]);
        const unsigned short lo = bf16_rne(xn[i] - bf16_f(hi));
        unsigned short* row = &uA0[xsm[i] * 136];
        row[xd[i]] = hi; row[38 + xd[i]] = lo; row[76 + xd[i]] = hi;
    }
    // zero h zones (h0 = h1 = 0 at t=0)
    if (lm < 10) {
        #pragma unroll
        for (int r = 0; r < 4; ++r) {
            const int m = 4 * q + r;
            unsigned short* r0 = &uA0[m * 136];
            r0[28 + lm] = 0; r0[66 + lm] = 0; r0[104 + lm] = 0;
            unsigned short* r1 = &uA1[m * 72];
            r1[lm] = 0; r1[20 + lm] = 0; r1[40 + lm] = 0;         // h0
            r1[10 + lm] = 0; r1[30 + lm] = 0; r1[50 + lm] = 0;    // h1
        }
    }
    FENCE();

    float c0s[4] = {0, 0, 0, 0}, c1s[4] = {0, 0, 0, 0};
    float h1v[4] = {0, 0, 0, 0};

    #pragma unroll 1
    for (int t = 0; t < TSTEPS; ++t) {
        // ---- A0 frags (read BEFORE any t+1 writes; DS pipe in-order) ----
        short8 A0[4];
        #pragma unroll
        for (int c = 0; c < 4; ++c)
            A0[c] = *(const short8*)&uA0[lm * 136 + 32 * c + 8 * q];
        FENCE();

        // prefetch x(t+1) into VGPRs (consumed at end of iteration)
        if (t + 1 < TSTEPS) {
            #pragma unroll
            for (int i = 0; i < 7; ++i) { xp[i] += DDIM; xn[i] = xp[i][0]; }
        }

        // ---- L0 MFMA: 3 N-tiles x 4 K-chunks ----
        f32x4 C[3];
        #pragma unroll
        for (int T = 0; T < 3; ++T) {
            f32x4 acc = {bias0[T], bias0[T], bias0[T], bias0[T]};
            #pragma unroll
            for (int c = 0; c < 4; ++c)
                acc = __builtin_amdgcn_mfma_f32_16x16x32_bf16(A0[c], B0[T][c], acc, 0, 0, 0);
            C[T] = acc;
        }
        // activate + store gates (lane holds n=lm+16T, m=4q+r)
        #pragma unroll
        for (int T = 0; T < 3; ++T) {
            const float a = aT[T];
            f32x4 gv;
            #pragma unroll
            for (int r = 0; r < 4; ++r) gv[r] = act_eval(C[T][r], a);
            *(f32x4*)&gbuf[(lm + 16 * T) * 20 + 4 * q] = gv;
        }
        FENCE();

        // ---- c0/h0 update: lane owns unit u=lm, samples m=4q+r ----
        {
            const f32x4 iv = *(const f32x4*)&gbuf[(lm     ) * 20 + 4 * q];
            const f32x4 fv = *(const f32x4*)&gbuf[(lm + 10) * 20 + 4 * q];
            const f32x4 gg = *(const f32x4*)&gbuf[(lm + 20) * 20 + 4 * q];
            const f32x4 ov = *(const f32x4*)&gbuf[(lm + 30) * 20 + 4 * q];
            float h0v[4];
            #pragma unroll
            for (int r = 0; r < 4; ++r) {
                const float c = fv[r] * c0s[r] + iv[r] * gg[r];
                c0s[r] = c;
                h0v[r] = ov[r] * act_eval(c, 2.0f);   // tanh
            }
            if (lm < 10) {
                #pragma unroll
                for (int r = 0; r < 4; ++r) {
                    const int m = 4 * q + r;
                    const unsigned short hi = bf16_rne(h0v[r]);
                    const unsigned short lo = bf16_rne(h0v[r] - bf16_f(hi));
                    unsigned short* r0 = &uA0[m * 136];
                    r0[28 + lm] = hi; r0[66 + lm] = lo; r0[104 + lm] = hi;
                    unsigned short* r1 = &uA1[m * 72];
                    r1[lm] = hi; r1[20 + lm] = lo; r1[40 + lm] = hi;
                }
            }
        }
        FENCE();

        // ---- L1 MFMA: 3 N-tiles x 2 K-chunks ----
        short8 A1[2];
        #pragma unroll
        for (int c = 0; c < 2; ++c)
            A1[c] = *(const short8*)&uA1[lm * 72 + 32 * c + 8 * q];
        f32x4 D[3];
        #pragma unroll
        for (int T = 0; T < 3; ++T) {
            f32x4 acc = {bias1[T], bias1[T], bias1[T], bias1[T]};
            #pragma unroll
            for (int c = 0; c < 2; ++c)
                acc = __builtin_amdgcn_mfma_f32_16x16x32_bf16(A1[c], B1[T][c], acc, 0, 0, 0);
            D[T] = acc;
        }
        #pragma unroll
        for (int T = 0; T < 3; ++T) {
            const float a = aT[T];
            f32x4 gv;
            #pragma unroll
            for (int r = 0; r < 4; ++r) gv[r] = act_eval(D[T][r], a);
            *(f32x4*)&gbuf[(lm + 16 * T) * 20 + 4 * q] = gv;
        }
        FENCE();

        // ---- c1/h1 update ----
        {
            const f32x4 iv = *(const f32x4*)&gbuf[(lm     ) * 20 + 4 * q];
            const f32x4 fv = *(const f32x4*)&gbuf[(lm + 10) * 20 + 4 * q];
            const f32x4 gg = *(const f32x4*)&gbuf[(lm + 20) * 20 + 4 * q];
            const f32x4 ov = *(const f32x4*)&gbuf[(lm + 30) * 20 + 4 * q];
            #pragma unroll
            for (int r = 0; r < 4; ++r) {
                const float c = fv[r] * c1s[r] + iv[r] * gg[r];
                c1s[r] = c;
                h1v[r] = ov[r] * act_eval(c, 2.0f);
            }
            if (lm < 10) {
                #pragma unroll
                for (int r = 0; r < 4; ++r) {
                    const int m = 4 * q + r;
                    const unsigned short hi = bf16_rne(h1v[r]);
                    const unsigned short lo = bf16_rne(h1v[r] - bf16_f(hi));
                    unsigned short* r1 = &uA1[m * 72];
                    r1[10 + lm] = hi; r1[30 + lm] = lo; r1[50 + lm] = hi;
                }
            }
        }
        FENCE();

        // ---- write x(t+1) zones (loads long landed; after t's A0 reads) ----
        if (t + 1 < TSTEPS) {
            #pragma unroll
            for (int i = 0; i < 7; ++i) {
                const unsigned short hi = bf16_rne(xn[i]);
                const unsigned short lo = bf16_rne(xn[i] - bf16_f(hi));
                unsigned short* row = &uA0[xsm[i] * 136];
                row[xd[i]] = hi; row[38 + xd[i]] = lo; row[76 + xd[i]] = hi;
            }
        }
        FENCE();
    }

    // ---- classifier ----
    if (lm < 10) {
        #pragma unroll
        for (int r = 0; r < 4; ++r) hfin[(4 * q + r) * 12 + lm] = h1v[r];
    }
    FENCE();
    if (lm < 10) {
        float wc[10];
        #pragma unroll
        for (int j = 0; j < 10; ++j) wc[j] = w_cls[lm * 10 + j];
        const float bo = b_cls[lm];
        #pragma unroll
        for (int r = 0; r < 4; ++r) {
            const int m = 4 * q + r;
            float acc = bo;
            #pragma unroll
            for (int j = 0; j < 10; ++j) acc += hfin[m * 12 + j] * wc[j];
            out[(size_t)(sbase + m) * 10 + lm] = acc;
        }
    }
}

extern "C" void kernel_launch(void* const* d_in, const int* in_sizes, int n_in,
                              void* d_out, int out_size, void* d_ws, size_t ws_size,
                              hipStream_t stream) {
    const float* x     = (const float*)d_in[0];
    const float* w_ih0 = (const float*)d_in[1];
    const float* w_hh0 = (const float*)d_in[2];
    const float* b_ih0 = (const float*)d_in[3];
    const float* b_hh0 = (const float*)d_in[4];
    const float* w_ih1 = (const float*)d_in[5];
    const float* w_hh1 = (const float*)d_in[6];
    const float* b_ih1 = (const float*)d_in[7];
    const float* b_hh1 = (const float*)d_in[8];
    const float* w_cls = (const float*)d_in[9];
    const float* b_cls = (const float*)d_in[10];
    float* out = (float*)d_out;

    const int B = in_sizes[0] / (TSTEPS * DDIM);   // 32768
    const int grid = B / 16;                       // 2048 blocks of 1 wave

    hipLaunchKernelGGL(lstm2_mfma_kernel, dim3(grid), dim3(64), 0, stream,
                       x, w_ih0, w_hh0, b_ih0, b_hh0,
                       w_ih1, w_hh1, b_ih1, b_hh1,
                       w_cls, b_cls, out);
}